// Round 1
// baseline (745.041 us; speedup 1.0000x reference)
//
#include <hip/hip_runtime.h>
#include <math.h>

// DiscreteComm: per-node encoder logits (hoisted from edges), per-edge
// gumbel-argmax -> 128-bit message, OR-aggregate via atomics, then
// f_dec + GRU cell. All f32 this round.

#define NN 20000
#define NE 640000
#define HID 256
#define MSGW 64

// C[M,N] = [A0|A1] @ W[N,K]^T + bias.  K0,K1 multiples of BK.
template<int BM, int BN, int BK, int TM, int TN>
__global__ __launch_bounds__(256)
void gemm_bias_f32(const float* __restrict__ A0, int K0,
                   const float* __restrict__ A1, int K1,
                   const float* __restrict__ W, const float* __restrict__ bias,
                   float* __restrict__ C, int M, int N)
{
    __shared__ float As[BK][BM + 4];
    __shared__ float Ws[BK][BN + 4];
    const int K = K0 + K1;
    const int bm0 = blockIdx.x * BM;
    const int bn0 = blockIdx.y * BN;
    const int tid = threadIdx.x;
    const int tx = tid % (BN / TN);
    const int ty = tid / (BN / TN);

    float acc[TM][TN];
#pragma unroll
    for (int i = 0; i < TM; ++i)
#pragma unroll
        for (int j = 0; j < TN; ++j) acc[i][j] = 0.f;

    constexpr int CH = BK / 4;  // float4 chunks per row-slice
    for (int kt = 0; kt < K; kt += BK) {
        // A tile: BM rows x BK cols, stored transposed As[k][m]
        for (int i = tid; i < BM * CH; i += 256) {
            int row = i / CH, ch = i % CH;
            int gm = bm0 + row; if (gm >= M) gm = M - 1;  // clamp, stores guarded
            int gk = kt + ch * 4;
            const float* p = (gk < K0) ? (A0 + (size_t)gm * K0 + gk)
                                       : (A1 + (size_t)gm * K1 + (gk - K0));
            float4 v = *(const float4*)p;
            As[ch*4+0][row] = v.x; As[ch*4+1][row] = v.y;
            As[ch*4+2][row] = v.z; As[ch*4+3][row] = v.w;
        }
        // W tile: BN rows x BK cols, transposed Ws[k][n]
        for (int i = tid; i < BN * CH; i += 256) {
            int row = i / CH, ch = i % CH;
            int gn = bn0 + row;
            int gk = kt + ch * 4;
            float4 v = *(const float4*)(W + (size_t)gn * K + gk);
            Ws[ch*4+0][row] = v.x; Ws[ch*4+1][row] = v.y;
            Ws[ch*4+2][row] = v.z; Ws[ch*4+3][row] = v.w;
        }
        __syncthreads();
#pragma unroll
        for (int k = 0; k < BK; ++k) {
            float a[TM], w[TN];
#pragma unroll
            for (int i = 0; i < TM; i += 4) {
                float4 v = *(const float4*)&As[k][ty * TM + i];
                a[i] = v.x; a[i+1] = v.y; a[i+2] = v.z; a[i+3] = v.w;
            }
#pragma unroll
            for (int j = 0; j < TN; j += 4) {
                float4 v = *(const float4*)&Ws[k][tx * TN + j];
                w[j] = v.x; w[j+1] = v.y; w[j+2] = v.z; w[j+3] = v.w;
            }
#pragma unroll
            for (int i = 0; i < TM; ++i)
#pragma unroll
                for (int j = 0; j < TN; ++j)
                    acc[i][j] += a[i] * w[j];
        }
        __syncthreads();
    }
#pragma unroll
    for (int i = 0; i < TM; ++i) {
        int gm = bm0 + ty * TM + i;
        if (gm < M) {
#pragma unroll
            for (int j = 0; j < TN; j += 4) {
                int gn = bn0 + tx * TN + j;
                float4 o;
                o.x = acc[i][j+0] + bias[gn+0];
                o.y = acc[i][j+1] + bias[gn+1];
                o.z = acc[i][j+2] + bias[gn+2];
                o.w = acc[i][j+3] + bias[gn+3];
                *(float4*)&C[(size_t)gm * N + gn] = o;
            }
        }
    }
}

__global__ __launch_bounds__(256)
void zero_kernel(unsigned int* __restrict__ p, int n)
{
    int i = blockIdx.x * 256 + threadIdx.x;
    if (i < n) p[i] = 0u;
}

// One wave per edge. Lane j handles symbol j: compare L[src,2j]+g0 vs
// L[src,2j+1]+g1 (argmax ties -> index 0). Build 128-bit mask, OR-reduce
// within 16-lane groups, 4 atomicOr per edge into cbits[dst].
__global__ __launch_bounds__(256)
void edge_msg_kernel(const float* __restrict__ L, const float* __restrict__ gumbel,
                     const int* __restrict__ src, const int* __restrict__ dst,
                     unsigned int* __restrict__ cbits, int E)
{
    int e = blockIdx.x * 4 + (threadIdx.x >> 6);
    if (e >= E) return;
    int lane = threadIdx.x & 63;
    int s = src[e];
    float2 g = *(const float2*)&gumbel[(size_t)e * 128 + lane * 2];
    float2 l = *(const float2*)&L[(size_t)s * 128 + lane * 2];
    int choice1 = (l.x + g.x) < (l.y + g.y) ? 1 : 0;
    unsigned int val = 1u << (2 * (lane & 15) + choice1);
    val |= __shfl_xor(val, 1);
    val |= __shfl_xor(val, 2);
    val |= __shfl_xor(val, 4);
    val |= __shfl_xor(val, 8);
    if ((lane & 15) == 0) {
        int d = dst[e];
        atomicOr(&cbits[(size_t)d * 4 + (lane >> 4)], val);
    }
}

// dec[n,k] = b_dec[k] + sum over set bits j of W_dec[k,j]. W_dec staged in
// LDS with stride 133 (bank-conflict-free for per-lane row access).
__global__ __launch_bounds__(256)
void dec_kernel(const unsigned int* __restrict__ cbits,
                const float* __restrict__ W_dec, const float* __restrict__ b_dec,
                float* __restrict__ dec, int N)
{
    __shared__ float Wl[128 * 133];
    __shared__ unsigned int cb[64][4];
    int tid = threadIdx.x;
    for (int i = tid; i < 128 * 128; i += 256) {
        int row = i >> 7, col = i & 127;
        Wl[row * 133 + col] = W_dec[i];
    }
    int n0 = blockIdx.x * 64;
    {
        int nl = tid >> 2, w = tid & 3;
        int node = n0 + nl;
        cb[nl][w] = (node < N) ? cbits[(size_t)node * 4 + w] : 0u;
    }
    __syncthreads();
    int k = tid & 127;
    float bk = b_dec[k];
    for (int pass = 0; pass < 32; ++pass) {
        int nl = (tid >> 7) + pass * 2;
        int node = n0 + nl;
        if (node >= N) break;
        float acc = bk;
#pragma unroll
        for (int w = 0; w < 4; ++w) {
            unsigned int bits = cb[nl][w];
#pragma unroll
            for (int j = 0; j < 32; ++j) {
                if (bits & (1u << j)) acc += Wl[k * 133 + w * 32 + j];
            }
        }
        dec[(size_t)node * 128 + k] = acc;
    }
}

__global__ __launch_bounds__(256)
void gru_kernel(const float* __restrict__ gi, const float* __restrict__ gh,
                const float* __restrict__ h, float* __restrict__ out)
{
    int idx = blockIdx.x * 256 + threadIdx.x;
    int n = idx >> 8, k = idx & 255;
    size_t b = (size_t)n * 768;
    float i_r = gi[b + k],       h_r = gh[b + k];
    float i_z = gi[b + 256 + k], h_z = gh[b + 256 + k];
    float i_n = gi[b + 512 + k], h_n = gh[b + 512 + k];
    float r = 1.f / (1.f + expf(-(i_r + h_r)));
    float z = 1.f / (1.f + expf(-(i_z + h_z)));
    float nn = tanhf(i_n + r * h_n);
    out[idx] = (1.f - z) * nn + z * h[(size_t)n * 256 + k];
}

extern "C" void kernel_launch(void* const* d_in, const int* in_sizes, int n_in,
                              void* d_out, int out_size, void* d_ws, size_t ws_size,
                              hipStream_t stream)
{
    const float* x     = (const float*)d_in[0];
    const float* h     = (const float*)d_in[1];
    const float* W_enc = (const float*)d_in[2];
    const float* b_enc = (const float*)d_in[3];
    const float* W_dec = (const float*)d_in[4];
    const float* b_dec = (const float*)d_in[5];
    const float* W_ih  = (const float*)d_in[6];
    const float* b_ih  = (const float*)d_in[7];
    const float* W_hh  = (const float*)d_in[8];
    const float* b_hh  = (const float*)d_in[9];
    const float* gumbel = (const float*)d_in[10];
    const int*   src   = (const int*)d_in[11];
    const int*   dst   = (const int*)d_in[12];
    float* out = (float*)d_out;

    char* ws = (char*)d_ws;
    float* L    = (float*)(ws);                    // 20000*128 f32 = 10.24 MB
    float* decb = (float*)(ws + 10240000);         // 20000*128 f32
    float* gi   = (float*)(ws + 20480000);         // 20000*768 f32 = 61.44 MB
    float* gh   = (float*)(ws + 81920000);         // 20000*768 f32
    unsigned int* cbits = (unsigned int*)(ws + 143360000);  // 20000*4 u32

    zero_kernel<<<(NN * 4 + 255) / 256, 256, 0, stream>>>(cbits, NN * 4);

    // L = [x|h] @ W_enc^T + b_enc   (M=20000, N=128, K=512)
    gemm_bias_f32<128,128,16,8,8><<<dim3(157, 1), 256, 0, stream>>>(
        x, 256, h, 256, W_enc, b_enc, L, NN, 128);

    edge_msg_kernel<<<NE / 4, 256, 0, stream>>>(L, gumbel, src, dst, cbits, NE);

    dec_kernel<<<(NN + 63) / 64, 256, 0, stream>>>(cbits, W_dec, b_dec, decb, NN);

    // gi = [x|dec] @ W_ih^T + b_ih   (M=20000, N=768, K=384)
    gemm_bias_f32<128,128,16,8,8><<<dim3(157, 6), 256, 0, stream>>>(
        x, 256, decb, 128, W_ih, b_ih, gi, NN, 768);

    // gh = h @ W_hh^T + b_hh         (M=20000, N=768, K=256)
    gemm_bias_f32<128,128,16,8,8><<<dim3(157, 6), 256, 0, stream>>>(
        h, 256, (const float*)nullptr, 0, W_hh, b_hh, gh, NN, 768);

    gru_kernel<<<NN, 256, 0, stream>>>(gi, gh, h, out);
}

// Round 2
// 353.558 us; speedup vs baseline: 2.1073x; 2.1073x over previous
//
#include <hip/hip_runtime.h>
#include <math.h>

#define NN 20000
#define NE 640000
#define HID 256
#define MSGW 64

typedef __attribute__((ext_vector_type(8))) short short8v;
typedef __attribute__((ext_vector_type(4))) float f32x4;

__device__ inline unsigned short f2bf(float f) {
    unsigned int u = __builtin_bit_cast(unsigned int, f);
    u += 0x7fff + ((u >> 16) & 1);   // round-to-nearest-even
    return (unsigned short)(u >> 16);
}

// ---------------- f32 vector GEMM (small shapes) ----------------
// C[M,N] = A0[M,K0] @ W[N,K]^T + bias
template<int BM, int BN, int BK, int TM, int TN>
__global__ __launch_bounds__(256)
void gemm_bias_f32(const float* __restrict__ A0, int K0,
                   const float* __restrict__ A1, int K1,
                   const float* __restrict__ W, const float* __restrict__ bias,
                   float* __restrict__ C, int M, int N)
{
    __shared__ float As[BK][BM + 4];
    __shared__ float Ws[BK][BN + 4];
    const int K = K0 + K1;
    const int bm0 = blockIdx.x * BM;
    const int bn0 = blockIdx.y * BN;
    const int tid = threadIdx.x;
    const int tx = tid % (BN / TN);
    const int ty = tid / (BN / TN);

    float acc[TM][TN];
#pragma unroll
    for (int i = 0; i < TM; ++i)
#pragma unroll
        for (int j = 0; j < TN; ++j) acc[i][j] = 0.f;

    constexpr int CH = BK / 4;
    for (int kt = 0; kt < K; kt += BK) {
        for (int i = tid; i < BM * CH; i += 256) {
            int row = i / CH, ch = i % CH;
            int gm = bm0 + row; if (gm >= M) gm = M - 1;
            int gk = kt + ch * 4;
            const float* p = (gk < K0) ? (A0 + (size_t)gm * K0 + gk)
                                       : (A1 + (size_t)gm * K1 + (gk - K0));
            float4 v = *(const float4*)p;
            As[ch*4+0][row] = v.x; As[ch*4+1][row] = v.y;
            As[ch*4+2][row] = v.z; As[ch*4+3][row] = v.w;
        }
        for (int i = tid; i < BN * CH; i += 256) {
            int row = i / CH, ch = i % CH;
            int gn = bn0 + row;
            int gk = kt + ch * 4;
            float4 v = *(const float4*)(W + (size_t)gn * K + gk);
            Ws[ch*4+0][row] = v.x; Ws[ch*4+1][row] = v.y;
            Ws[ch*4+2][row] = v.z; Ws[ch*4+3][row] = v.w;
        }
        __syncthreads();
#pragma unroll
        for (int k = 0; k < BK; ++k) {
            float a[TM], w[TN];
#pragma unroll
            for (int i = 0; i < TM; i += 4) {
                float4 v = *(const float4*)&As[k][ty * TM + i];
                a[i] = v.x; a[i+1] = v.y; a[i+2] = v.z; a[i+3] = v.w;
            }
#pragma unroll
            for (int j = 0; j < TN; j += 4) {
                float4 v = *(const float4*)&Ws[k][tx * TN + j];
                w[j] = v.x; w[j+1] = v.y; w[j+2] = v.z; w[j+3] = v.w;
            }
#pragma unroll
            for (int i = 0; i < TM; ++i)
#pragma unroll
                for (int j = 0; j < TN; ++j)
                    acc[i][j] += a[i] * w[j];
        }
        __syncthreads();
    }
#pragma unroll
    for (int i = 0; i < TM; ++i) {
        int gm = bm0 + ty * TM + i;
        if (gm < M) {
#pragma unroll
            for (int j = 0; j < TN; j += 4) {
                int gn = bn0 + tx * TN + j;
                float4 o;
                o.x = acc[i][j+0] + bias[gn+0];
                o.y = acc[i][j+1] + bias[gn+1];
                o.z = acc[i][j+2] + bias[gn+2];
                o.w = acc[i][j+3] + bias[gn+3];
                *(float4*)&C[(size_t)gm * N + gn] = o;
            }
        }
    }
}

// ---------------- bf16 MFMA GEMM ----------------
// C[M,N] = [A0|A1](f32, cvt->bf16) @ W[N,K]^T(f32, cvt->bf16) + bias, f32 out.
// BM=BN=128, BK=64. K0, K1 multiples of 64. N multiple of 128.
__global__ __launch_bounds__(256)
void gemm_mfma_bf16(const float* __restrict__ A0, int K0,
                    const float* __restrict__ A1, int K1,
                    const float* __restrict__ W, const float* __restrict__ bias,
                    float* __restrict__ C, int M, int N)
{
    __shared__ __align__(16) short As[128][72];   // stride 144B: 16B-aligned, no 16-way bank conflict
    __shared__ __align__(16) short Ws[128][72];
    const int K = K0 + K1;
    const int bm0 = blockIdx.x * 128;
    const int bn0 = blockIdx.y * 128;
    const int tid = threadIdx.x;
    const int lane = tid & 63;
    const int wave = tid >> 6;
    const int wm = wave >> 1, wn = wave & 1;     // 2x2 wave grid, 64x64 out each
    const int r16 = lane & 15, kg = lane >> 4;

    f32x4 acc[4][4];
#pragma unroll
    for (int i = 0; i < 4; ++i)
#pragma unroll
        for (int j = 0; j < 4; ++j) acc[i][j] = (f32x4){0.f, 0.f, 0.f, 0.f};

    for (int kt = 0; kt < K; kt += 64) {
        // stage A and W tiles: 128 rows x 64 cols, 8-f32 segments -> 8 bf16
#pragma unroll
        for (int it = 0; it < 4; ++it) {
            int seg = tid + it * 256;            // 0..1023
            int row = seg >> 3, s = seg & 7;
            int kc = kt + s * 8;
            int gm = bm0 + row; if (gm >= M) gm = M - 1;
            const float* p = (kt < K0) ? (A0 + (size_t)gm * K0 + kc)
                                       : (A1 + (size_t)gm * K1 + (kc - K0));
            float4 v0 = *(const float4*)p;
            float4 v1 = *(const float4*)(p + 4);
            short8v sv;
            sv[0] = (short)f2bf(v0.x); sv[1] = (short)f2bf(v0.y);
            sv[2] = (short)f2bf(v0.z); sv[3] = (short)f2bf(v0.w);
            sv[4] = (short)f2bf(v1.x); sv[5] = (short)f2bf(v1.y);
            sv[6] = (short)f2bf(v1.z); sv[7] = (short)f2bf(v1.w);
            *(short8v*)&As[row][s * 8] = sv;

            int gn = bn0 + row;
            const float* q = W + (size_t)gn * K + kc;
            float4 w0 = *(const float4*)q;
            float4 w1 = *(const float4*)(q + 4);
            short8v wv;
            wv[0] = (short)f2bf(w0.x); wv[1] = (short)f2bf(w0.y);
            wv[2] = (short)f2bf(w0.z); wv[3] = (short)f2bf(w0.w);
            wv[4] = (short)f2bf(w1.x); wv[5] = (short)f2bf(w1.y);
            wv[6] = (short)f2bf(w1.z); wv[7] = (short)f2bf(w1.w);
            *(short8v*)&Ws[row][s * 8] = wv;
        }
        __syncthreads();
#pragma unroll
        for (int ks = 0; ks < 2; ++ks) {
            int kc = ks * 32 + kg * 8;
            short8v a[4], b[4];
#pragma unroll
            for (int f = 0; f < 4; ++f)
                a[f] = *(const short8v*)&As[wm * 64 + f * 16 + r16][kc];
#pragma unroll
            for (int f = 0; f < 4; ++f)
                b[f] = *(const short8v*)&Ws[wn * 64 + f * 16 + r16][kc];
#pragma unroll
            for (int fi = 0; fi < 4; ++fi)
#pragma unroll
                for (int fj = 0; fj < 4; ++fj)
                    acc[fi][fj] = __builtin_amdgcn_mfma_f32_16x16x32_bf16(
                        a[fi], b[fj], acc[fi][fj], 0, 0, 0);
        }
        __syncthreads();
    }
    // epilogue: C/D layout col=lane&15, row=(lane>>4)*4+i  [m89]
#pragma unroll
    for (int fi = 0; fi < 4; ++fi) {
        int rg = bm0 + wm * 64 + fi * 16 + kg * 4;
#pragma unroll
        for (int fj = 0; fj < 4; ++fj) {
            int cg = bn0 + wn * 64 + fj * 16 + r16;
            float bv = bias[cg];
#pragma unroll
            for (int i = 0; i < 4; ++i) {
                if (rg + i < M)
                    C[(size_t)(rg + i) * N + cg] = acc[fi][fj][i] + bv;
            }
        }
    }
}

__global__ __launch_bounds__(256)
void zero_kernel(unsigned int* __restrict__ p, int n)
{
    int i = blockIdx.x * 256 + threadIdx.x;
    if (i < n) p[i] = 0u;
}

// one wave per edge; lane j: argmax over pair -> bit, OR-reduce, 4 atomicOr
__global__ __launch_bounds__(256)
void edge_msg_kernel(const float* __restrict__ L, const float* __restrict__ gumbel,
                     const int* __restrict__ src, const int* __restrict__ dst,
                     unsigned int* __restrict__ cbits, int E)
{
    int e = blockIdx.x * 4 + (threadIdx.x >> 6);
    if (e >= E) return;
    int lane = threadIdx.x & 63;
    int s = src[e];
    float2 g = *(const float2*)&gumbel[(size_t)e * 128 + lane * 2];
    float2 l = *(const float2*)&L[(size_t)s * 128 + lane * 2];
    int choice1 = (l.x + g.x) < (l.y + g.y) ? 1 : 0;
    unsigned int val = 1u << (2 * (lane & 15) + choice1);
    val |= __shfl_xor(val, 1);
    val |= __shfl_xor(val, 2);
    val |= __shfl_xor(val, 4);
    val |= __shfl_xor(val, 8);
    if ((lane & 15) == 0) {
        int d = dst[e];
        atomicOr(&cbits[(size_t)d * 4 + (lane >> 4)], val);
    }
}

// expand cbits -> float c[N,128]
__global__ __launch_bounds__(256)
void expand_c_kernel(const unsigned int* __restrict__ cbits, float* __restrict__ c, int n)
{
    int idx = blockIdx.x * 256 + threadIdx.x;
    if (idx >= n) return;
    int node = idx >> 7, j = idx & 127;
    unsigned int bits = cbits[node * 4 + (j >> 5)];
    c[idx] = (float)((bits >> (j & 31)) & 1u);
}

__global__ __launch_bounds__(256)
void gru_kernel(const float* __restrict__ gi, const float* __restrict__ gh,
                const float* __restrict__ h, float* __restrict__ out)
{
    int idx = blockIdx.x * 256 + threadIdx.x;
    int n = idx >> 8, k = idx & 255;
    size_t b = (size_t)n * 768;
    float i_r = gi[b + k],       h_r = gh[b + k];
    float i_z = gi[b + 256 + k], h_z = gh[b + 256 + k];
    float i_n = gi[b + 512 + k], h_n = gh[b + 512 + k];
    float r = 1.f / (1.f + expf(-(i_r + h_r)));
    float z = 1.f / (1.f + expf(-(i_z + h_z)));
    float nn = tanhf(i_n + r * h_n);
    out[idx] = (1.f - z) * nn + z * h[(size_t)n * 256 + k];
}

extern "C" void kernel_launch(void* const* d_in, const int* in_sizes, int n_in,
                              void* d_out, int out_size, void* d_ws, size_t ws_size,
                              hipStream_t stream)
{
    const float* x     = (const float*)d_in[0];
    const float* h     = (const float*)d_in[1];
    const float* W_enc = (const float*)d_in[2];
    const float* b_enc = (const float*)d_in[3];
    const float* W_dec = (const float*)d_in[4];
    const float* b_dec = (const float*)d_in[5];
    const float* W_ih  = (const float*)d_in[6];
    const float* b_ih  = (const float*)d_in[7];
    const float* W_hh  = (const float*)d_in[8];
    const float* b_hh  = (const float*)d_in[9];
    const float* gumbel = (const float*)d_in[10];
    const int*   src   = (const int*)d_in[11];
    const int*   dst   = (const int*)d_in[12];
    float* out = (float*)d_out;

    char* ws = (char*)d_ws;
    float* L    = (float*)(ws);                      // 20000*128 f32
    float* c    = (float*)(ws + 10240000);           // 20000*128 f32
    float* decb = (float*)(ws + 20480000);           // 20000*128 f32
    float* gi   = (float*)(ws + 30720000);           // 20000*768 f32
    float* gh   = (float*)(ws + 92160000);           // 20000*768 f32
    unsigned int* cbits = (unsigned int*)(ws + 153600000);  // 20000*4 u32

    zero_kernel<<<(NN * 4 + 255) / 256, 256, 0, stream>>>(cbits, NN * 4);

    // L = [x|h] @ W_enc^T + b_enc   (M=20000, N=128, K=512) -- f32 (argmax precision)
    gemm_bias_f32<64,64,16,4,4><<<dim3(313, 2), 256, 0, stream>>>(
        x, 256, h, 256, W_enc, b_enc, L, NN, 128);

    edge_msg_kernel<<<NE / 4, 256, 0, stream>>>(L, gumbel, src, dst, cbits, NE);

    expand_c_kernel<<<(NN * 128 + 255) / 256, 256, 0, stream>>>(cbits, c, NN * 128);

    // decb = c @ W_dec^T + b_dec    (M=20000, N=128, K=128) -- f32
    gemm_bias_f32<64,64,16,4,4><<<dim3(313, 2), 256, 0, stream>>>(
        c, 128, (const float*)nullptr, 0, W_dec, b_dec, decb, NN, 128);

    // gi = [x|decb] @ W_ih^T + b_ih (M=20000, N=768, K=384) -- bf16 MFMA
    gemm_mfma_bf16<<<dim3(157, 6), 256, 0, stream>>>(
        x, 256, decb, 128, W_ih, b_ih, gi, NN, 768);

    // gh = h @ W_hh^T + b_hh        (M=20000, N=768, K=256) -- bf16 MFMA
    gemm_mfma_bf16<<<dim3(157, 6), 256, 0, stream>>>(
        h, 256, (const float*)nullptr, 0, W_hh, b_hh, gh, NN, 768);

    gru_kernel<<<NN, 256, 0, stream>>>(gi, gh, h, out);
}

// Round 3
// 317.935 us; speedup vs baseline: 2.3434x; 1.1120x over previous
//
#include <hip/hip_runtime.h>
#include <math.h>

#define NN 20000
#define NE 640000

typedef __attribute__((ext_vector_type(8))) short short8v;
typedef __attribute__((ext_vector_type(4))) float f32x4;

__device__ inline unsigned short f2bf(float f) {
    unsigned int u = __builtin_bit_cast(unsigned int, f);
    u += 0x7fff + ((u >> 16) & 1);   // RNE
    return (unsigned short)(u >> 16);
}
__device__ inline float bf2f(unsigned short s) {
    unsigned int u = ((unsigned int)s) << 16;
    return __builtin_bit_cast(float, u);
}

__global__ __launch_bounds__(256)
void zero_kernel(unsigned int* __restrict__ p, int n)
{
    int i = blockIdx.x * 256 + threadIdx.x;
    if (i < n) p[i] = 0u;
}

// Wfused[i][m] = sum_p W_ih[i][256+p] * W_dec[p][m]   (768 x 128, inner 128)
__global__ __launch_bounds__(256)
void wfused_kernel(const float* __restrict__ W_ih, const float* __restrict__ W_dec,
                   float* __restrict__ Wfused)
{
    int idx = blockIdx.x * 256 + threadIdx.x;   // 768*128
    int i = idx >> 7, m = idx & 127;
    const float* wr = W_ih + (size_t)i * 384 + 256;
    float acc = 0.f;
#pragma unroll 4
    for (int p = 0; p < 128; ++p) acc += wr[p] * W_dec[p * 128 + m];
    Wfused[idx] = acc;
}

// Wbig[1024][640] bf16: rows grouped r(0:256), z, i_n, h_n; cols [x(256)|c(128)|h(256)]
__global__ __launch_bounds__(256)
void pack_kernel(const float* __restrict__ W_ih, const float* __restrict__ W_hh,
                 const float* __restrict__ Wfused, unsigned short* __restrict__ Wbig)
{
    int r = blockIdx.x;            // 1024
    int g = r >> 8, j = r & 255;
    for (int k = threadIdx.x; k < 640; k += 256) {
        float v;
        if (k < 256) {
            v = (g < 3) ? W_ih[(size_t)(g * 256 + j) * 384 + k] : 0.f;
        } else if (k < 384) {
            v = (g < 3) ? Wfused[(size_t)(g * 256 + j) * 128 + (k - 256)] : 0.f;
        } else {
            int sr = (g < 2) ? g * 256 + j : 512 + j;
            v = (g == 2) ? 0.f : W_hh[(size_t)sr * 256 + (k - 384)];
        }
        Wbig[(size_t)r * 640 + k] = f2bf(v);
    }
}

// bias_cat[1024]: r: b_ih+b_hh+bdt; z: same; i_n: b_ih+bdt; h_n: b_hh
// bdt[i] = sum_m W_ih[i][256+m] * b_dec[m]
__global__ __launch_bounds__(256)
void bias_kernel(const float* __restrict__ W_ih, const float* __restrict__ b_ih,
                 const float* __restrict__ b_hh, const float* __restrict__ b_dec,
                 float* __restrict__ bias_cat)
{
    int r = blockIdx.x * 256 + threadIdx.x;  // 1024
    int g = r >> 8, j = r & 255;
    float v;
    if (g == 3) {
        v = b_hh[512 + j];
    } else {
        int sr = g * 256 + j;
        float bdt = 0.f;
#pragma unroll 4
        for (int m = 0; m < 128; ++m) bdt += W_ih[(size_t)sr * 384 + 256 + m] * b_dec[m];
        v = b_ih[sr] + bdt + ((g < 2) ? b_hh[sr] : 0.f);
    }
    bias_cat[r] = v;
}

// L = [x|h] @ W_enc^T + b_enc via bf16x3 MFMA (f32-accurate for argmax).
// M=20000, N=128, K=512. BM=64, BN=128, BK=64.
__global__ __launch_bounds__(256)
void enc_gemm_bf16x3(const float* __restrict__ x, const float* __restrict__ h,
                     const float* __restrict__ W_enc, const float* __restrict__ b_enc,
                     float* __restrict__ L)
{
    __shared__ __align__(16) short Ah[64][72], Al[64][72];
    __shared__ __align__(16) short Wh[128][72], Wl[128][72];
    const int bm0 = blockIdx.x * 64;
    const int tid = threadIdx.x;
    const int lane = tid & 63;
    const int wave = tid >> 6;
    const int wm = wave >> 1, wn = wave & 1;   // wave tile: 32 rows x 64 cols
    const int r16 = lane & 15, kg = lane >> 4;

    f32x4 acc[2][4];
#pragma unroll
    for (int i = 0; i < 2; ++i)
#pragma unroll
        for (int j = 0; j < 4; ++j) acc[i][j] = (f32x4){0.f, 0.f, 0.f, 0.f};

    for (int kt = 0; kt < 512; kt += 64) {
#pragma unroll
        for (int it = 0; it < 2; ++it) {        // A: 64 rows x 8 segs
            int seg = tid + it * 256;
            int row = seg >> 3, s = seg & 7;
            int kc = kt + s * 8;
            int gm = bm0 + row; if (gm >= NN) gm = NN - 1;
            const float* p = (kc < 256) ? (x + (size_t)gm * 256 + kc)
                                        : (h + (size_t)gm * 256 + (kc - 256));
            float4 v0 = *(const float4*)p;
            float4 v1 = *(const float4*)(p + 4);
            float vv[8] = {v0.x, v0.y, v0.z, v0.w, v1.x, v1.y, v1.z, v1.w};
            short8v hi, lo;
#pragma unroll
            for (int t = 0; t < 8; ++t) {
                unsigned short hb = f2bf(vv[t]);
                hi[t] = (short)hb;
                lo[t] = (short)f2bf(vv[t] - bf2f(hb));
            }
            *(short8v*)&Ah[row][s * 8] = hi;
            *(short8v*)&Al[row][s * 8] = lo;
        }
#pragma unroll
        for (int it = 0; it < 4; ++it) {        // W: 128 rows x 8 segs
            int seg = tid + it * 256;
            int row = seg >> 3, s = seg & 7;
            int kc = kt + s * 8;
            const float* q = W_enc + (size_t)row * 512 + kc;
            float4 v0 = *(const float4*)q;
            float4 v1 = *(const float4*)(q + 4);
            float vv[8] = {v0.x, v0.y, v0.z, v0.w, v1.x, v1.y, v1.z, v1.w};
            short8v hi, lo;
#pragma unroll
            for (int t = 0; t < 8; ++t) {
                unsigned short hb = f2bf(vv[t]);
                hi[t] = (short)hb;
                lo[t] = (short)f2bf(vv[t] - bf2f(hb));
            }
            *(short8v*)&Wh[row][s * 8] = hi;
            *(short8v*)&Wl[row][s * 8] = lo;
        }
        __syncthreads();
#pragma unroll
        for (int ks = 0; ks < 2; ++ks) {
            int kc = ks * 32 + kg * 8;
            short8v ah[2], al[2], wh[4], wl[4];
#pragma unroll
            for (int f = 0; f < 2; ++f) {
                ah[f] = *(const short8v*)&Ah[wm * 32 + f * 16 + r16][kc];
                al[f] = *(const short8v*)&Al[wm * 32 + f * 16 + r16][kc];
            }
#pragma unroll
            for (int f = 0; f < 4; ++f) {
                wh[f] = *(const short8v*)&Wh[wn * 64 + f * 16 + r16][kc];
                wl[f] = *(const short8v*)&Wl[wn * 64 + f * 16 + r16][kc];
            }
#pragma unroll
            for (int fi = 0; fi < 2; ++fi)
#pragma unroll
                for (int fj = 0; fj < 4; ++fj) {
                    acc[fi][fj] = __builtin_amdgcn_mfma_f32_16x16x32_bf16(
                        ah[fi], wh[fj], acc[fi][fj], 0, 0, 0);
                    acc[fi][fj] = __builtin_amdgcn_mfma_f32_16x16x32_bf16(
                        al[fi], wh[fj], acc[fi][fj], 0, 0, 0);
                    acc[fi][fj] = __builtin_amdgcn_mfma_f32_16x16x32_bf16(
                        ah[fi], wl[fj], acc[fi][fj], 0, 0, 0);
                }
        }
        __syncthreads();
    }
#pragma unroll
    for (int fi = 0; fi < 2; ++fi) {
        int rg = bm0 + wm * 32 + fi * 16 + kg * 4;
#pragma unroll
        for (int fj = 0; fj < 4; ++fj) {
            int cg = wn * 64 + fj * 16 + r16;
            float bv = b_enc[cg];
#pragma unroll
            for (int i = 0; i < 4; ++i)
                if (rg + i < NN) L[(size_t)(rg + i) * 128 + cg] = acc[fi][fj][i] + bv;
        }
    }
}

// one wave per edge; lane j: argmax over pair -> bit, OR-reduce, 4 atomicOr
__global__ __launch_bounds__(256)
void edge_msg_kernel(const float* __restrict__ L, const float* __restrict__ gumbel,
                     const int* __restrict__ src, const int* __restrict__ dst,
                     unsigned int* __restrict__ cbits, int E)
{
    int e = blockIdx.x * 4 + (threadIdx.x >> 6);
    if (e >= E) return;
    int lane = threadIdx.x & 63;
    int s = src[e];
    float2 g = *(const float2*)&gumbel[(size_t)e * 128 + lane * 2];
    float2 l = *(const float2*)&L[(size_t)s * 128 + lane * 2];
    int choice1 = (l.x + g.x) < (l.y + g.y) ? 1 : 0;
    unsigned int val = 1u << (2 * (lane & 15) + choice1);
    val |= __shfl_xor(val, 1);
    val |= __shfl_xor(val, 2);
    val |= __shfl_xor(val, 4);
    val |= __shfl_xor(val, 8);
    if ((lane & 15) == 0) {
        int d = dst[e];
        atomicOr(&cbits[(size_t)d * 4 + (lane >> 4)], val);
    }
}

// gates[M,1024] = [x|c|h] @ Wbig^T + bias_cat.  BM=BN=128, BK=64.
// y<4: K=[0,640); y in {4,5} (i_n): K=[0,384); y in {6,7} (h_n): K=[384,640).
__global__ __launch_bounds__(256)
void gates_gemm(const float* __restrict__ x, const float* __restrict__ h,
                const unsigned int* __restrict__ cbits,
                const unsigned short* __restrict__ Wbig,
                const float* __restrict__ bias_cat,
                float* __restrict__ gates)
{
    __shared__ __align__(16) short As[128][72], Ws[128][72];
    const int bm0 = blockIdx.x * 128;
    const int y = blockIdx.y;
    const int bn0 = y * 128;
    const int kb = (y >= 6) ? 384 : 0;
    const int ke = (y == 4 || y == 5) ? 384 : 640;
    const int tid = threadIdx.x;
    const int lane = tid & 63;
    const int wave = tid >> 6;
    const int wm = wave >> 1, wn = wave & 1;   // 2x2, 64x64 per wave
    const int r16 = lane & 15, kg = lane >> 4;

    f32x4 acc[4][4];
#pragma unroll
    for (int i = 0; i < 4; ++i)
#pragma unroll
        for (int j = 0; j < 4; ++j) acc[i][j] = (f32x4){0.f, 0.f, 0.f, 0.f};

    for (int kt = kb; kt < ke; kt += 64) {
#pragma unroll
        for (int it = 0; it < 4; ++it) {
            int seg = tid + it * 256;           // 128 rows x 8 segs
            int row = seg >> 3, s = seg & 7;
            int kc = kt + s * 8;
            int gm = bm0 + row; if (gm >= NN) gm = NN - 1;
            short8v sv;
            if (kc < 256) {
                const float* p = x + (size_t)gm * 256 + kc;
                float4 v0 = *(const float4*)p;
                float4 v1 = *(const float4*)(p + 4);
                sv[0]=(short)f2bf(v0.x); sv[1]=(short)f2bf(v0.y);
                sv[2]=(short)f2bf(v0.z); sv[3]=(short)f2bf(v0.w);
                sv[4]=(short)f2bf(v1.x); sv[5]=(short)f2bf(v1.y);
                sv[6]=(short)f2bf(v1.z); sv[7]=(short)f2bf(v1.w);
            } else if (kc < 384) {
                int mb = kc - 256;
                unsigned int word = cbits[gm * 4 + (mb >> 5)];
                unsigned int byte = (word >> (mb & 31)) & 0xffu;
#pragma unroll
                for (int t = 0; t < 8; ++t)
                    sv[t] = ((byte >> t) & 1u) ? (short)0x3F80 : (short)0;
            } else {
                const float* p = h + (size_t)gm * 256 + (kc - 384);
                float4 v0 = *(const float4*)p;
                float4 v1 = *(const float4*)(p + 4);
                sv[0]=(short)f2bf(v0.x); sv[1]=(short)f2bf(v0.y);
                sv[2]=(short)f2bf(v0.z); sv[3]=(short)f2bf(v0.w);
                sv[4]=(short)f2bf(v1.x); sv[5]=(short)f2bf(v1.y);
                sv[6]=(short)f2bf(v1.z); sv[7]=(short)f2bf(v1.w);
            }
            *(short8v*)&As[row][s * 8] = sv;
            *(short8v*)&Ws[row][s * 8] =
                *(const short8v*)&Wbig[(size_t)(bn0 + row) * 640 + kc];
        }
        __syncthreads();
#pragma unroll
        for (int ks = 0; ks < 2; ++ks) {
            int kc = ks * 32 + kg * 8;
            short8v a[4], b[4];
#pragma unroll
            for (int f = 0; f < 4; ++f)
                a[f] = *(const short8v*)&As[wm * 64 + f * 16 + r16][kc];
#pragma unroll
            for (int f = 0; f < 4; ++f)
                b[f] = *(const short8v*)&Ws[wn * 64 + f * 16 + r16][kc];
#pragma unroll
            for (int fi = 0; fi < 4; ++fi)
#pragma unroll
                for (int fj = 0; fj < 4; ++fj)
                    acc[fi][fj] = __builtin_amdgcn_mfma_f32_16x16x32_bf16(
                        a[fi], b[fj], acc[fi][fj], 0, 0, 0);
        }
        __syncthreads();
    }
#pragma unroll
    for (int fi = 0; fi < 4; ++fi) {
        int rg = bm0 + wm * 64 + fi * 16 + kg * 4;
#pragma unroll
        for (int fj = 0; fj < 4; ++fj) {
            int cg = bn0 + wn * 64 + fj * 16 + r16;
            float bv = bias_cat[cg];
#pragma unroll
            for (int i = 0; i < 4; ++i)
                if (rg + i < NN)
                    gates[(size_t)(rg + i) * 1024 + cg] = acc[fi][fj][i] + bv;
        }
    }
}

__device__ inline float gru1(float rp, float zp, float ip, float hp, float hv)
{
    float r = 1.f / (1.f + __expf(-rp));
    float z = 1.f / (1.f + __expf(-zp));
    float nn = tanhf(ip + r * hp);
    return (1.f - z) * nn + z * hv;
}

__global__ __launch_bounds__(256)
void gru_kernel(const float* __restrict__ gates, const float* __restrict__ h,
                float* __restrict__ out)
{
    int idx = blockIdx.x * 256 + threadIdx.x;   // 20000*64
    int n = idx >> 6, q = (idx & 63) * 4;
    const float* g = gates + (size_t)n * 1024;
    float4 rp = *(const float4*)(g + q);
    float4 zp = *(const float4*)(g + 256 + q);
    float4 ip = *(const float4*)(g + 512 + q);
    float4 hp = *(const float4*)(g + 768 + q);
    float4 hv = *(const float4*)(h + (size_t)n * 256 + q);
    float4 o;
    o.x = gru1(rp.x, zp.x, ip.x, hp.x, hv.x);
    o.y = gru1(rp.y, zp.y, ip.y, hp.y, hv.y);
    o.z = gru1(rp.z, zp.z, ip.z, hp.z, hv.z);
    o.w = gru1(rp.w, zp.w, ip.w, hp.w, hv.w);
    *(float4*)(out + (size_t)n * 256 + q) = o;
}

extern "C" void kernel_launch(void* const* d_in, const int* in_sizes, int n_in,
                              void* d_out, int out_size, void* d_ws, size_t ws_size,
                              hipStream_t stream)
{
    const float* x     = (const float*)d_in[0];
    const float* h     = (const float*)d_in[1];
    const float* W_enc = (const float*)d_in[2];
    const float* b_enc = (const float*)d_in[3];
    const float* W_dec = (const float*)d_in[4];
    const float* b_dec = (const float*)d_in[5];
    const float* W_ih  = (const float*)d_in[6];
    const float* b_ih  = (const float*)d_in[7];
    const float* W_hh  = (const float*)d_in[8];
    const float* b_hh  = (const float*)d_in[9];
    const float* gumbel = (const float*)d_in[10];
    const int*   src   = (const int*)d_in[11];
    const int*   dst   = (const int*)d_in[12];
    float* out = (float*)d_out;

    char* ws = (char*)d_ws;
    float*          L        = (float*)(ws);                       // 10,240,000 B
    unsigned int*   cbits    = (unsigned int*)(ws + 10240000);     //    320,000 B
    float*          Wfused   = (float*)(ws + 10560000);            //    393,216 B
    unsigned short* Wbig     = (unsigned short*)(ws + 10953216);   //  1,310,720 B
    float*          bias_cat = (float*)(ws + 12263936);            //      4,096 B
    float*          gates    = (float*)(ws + 12268032);            // 81,920,000 B

    zero_kernel<<<313, 256, 0, stream>>>(cbits, NN * 4);
    wfused_kernel<<<384, 256, 0, stream>>>(W_ih, W_dec, Wfused);
    pack_kernel<<<1024, 256, 0, stream>>>(W_ih, W_hh, Wfused, Wbig);
    bias_kernel<<<4, 256, 0, stream>>>(W_ih, b_ih, b_hh, b_dec, bias_cat);

    enc_gemm_bf16x3<<<313, 256, 0, stream>>>(x, h, W_enc, b_enc, L);

    edge_msg_kernel<<<NE / 4, 256, 0, stream>>>(L, gumbel, src, dst, cbits, NE);

    gates_gemm<<<dim3(157, 8), 256, 0, stream>>>(x, h, cbits, Wbig, bias_cat, gates);

    gru_kernel<<<5000, 256, 0, stream>>>(gates, h, out);
}